// Round 2
// baseline (622.487 us; speedup 1.0000x reference)
//
#include <hip/hip_runtime.h>
#include <math.h>

#define D 512
#define LSEQ 4096
#define NB 16
#define WINDOW 32
#define NCHUNK 5
#define CHUNK 13            // 5*13 = 65 = 2*WINDOW+1
#define N_TISSUES 200
#define N_MECH 6
#define LN_EPS 1e-5f

__device__ __forceinline__ float gelu_exact(float x) {
    return 0.5f * x * (1.0f + erff(x * 0.70710678118654752f));
}

// ---------------------------------------------------------------------------
// Kernel 1: windowed diff partial sums.
// grid = NB * 3 * NCHUNK blocks, 256 threads. Each block accumulates 13
// window positions for one (batch, stream) into partial[(b*3+s)*NCHUNK+c][d].
// ---------------------------------------------------------------------------
__global__ __launch_bounds__(256) void pool_partial_kernel(
    const float* __restrict__ ref0, const float* __restrict__ ref1, const float* __restrict__ ref2,
    const float* __restrict__ alt0, const float* __restrict__ alt1, const float* __restrict__ alt2,
    const int* __restrict__ pos, float* __restrict__ partial)
{
    const int blk = blockIdx.x;
    const int b = blk / (3 * NCHUNK);
    const int s = (blk / NCHUNK) % 3;
    const int c = blk % NCHUNK;
    const float* __restrict__ ref = (s == 0) ? ref0 : ((s == 1) ? ref1 : ref2);
    const float* __restrict__ alt = (s == 0) ? alt0 : ((s == 1) ? alt1 : alt2);
    const int p = pos[b];
    const int tid = threadIdx.x;

    float acc0 = 0.0f, acc1 = 0.0f;
    const int base_off = -WINDOW + c * CHUNK;
    #pragma unroll
    for (int i = 0; i < CHUNK; ++i) {
        const int idx = p + base_off + i;
        if (idx >= 0 && idx < LSEQ) {
            const size_t row = ((size_t)b * LSEQ + (size_t)idx) * D;
            acc0 += alt[row + tid]       - ref[row + tid];
            acc1 += alt[row + tid + 256] - ref[row + tid + 256];
        }
    }
    float* __restrict__ outp = partial + ((size_t)(b * 3 + s) * NCHUNK + c) * D;
    outp[tid]       = acc0;   // written unconditionally: ws is poisoned 0xAA
    outp[tid + 256] = acc1;
}

// ---------------------------------------------------------------------------
// Kernel 2: per-batch fused head. 16 blocks x 512 threads.
// Reduce partials -> 3x LayerNorm -> cat(1536) in LDS -> fused GEMV+GELU ->
// t1/i1/m1 GEMVs -> tissue/mech/impact outputs.
// All GEMVs: 4-way accumulators (break dependent FMA chain) + float4 LDS
// reads of the shared activation vector (ds_read_b128).
// ---------------------------------------------------------------------------
__global__ __launch_bounds__(512) void head_kernel(
    const float* __restrict__ partial, const int* __restrict__ pos,
    const float* __restrict__ g0, const float* __restrict__ be0,
    const float* __restrict__ g1, const float* __restrict__ be1,
    const float* __restrict__ g2, const float* __restrict__ be2,
    const float* __restrict__ Wf,  const float* __restrict__ bf,
    const float* __restrict__ Wi1, const float* __restrict__ bi1,
    const float* __restrict__ Wi2, const float* __restrict__ bi2,
    const float* __restrict__ Wt1, const float* __restrict__ bt1,
    const float* __restrict__ Wt2, const float* __restrict__ bt2,
    const float* __restrict__ Wm1, const float* __restrict__ bm1,
    const float* __restrict__ Wm2, const float* __restrict__ bm2,
    float* __restrict__ out)
{
    __shared__ float cat_lds[3 * D];
    __shared__ float fused_lds[D];
    __shared__ float t1_lds[D];
    __shared__ float i1_lds[D / 2];
    __shared__ float m1_lds[D / 2];
    __shared__ float red[16];

    const int b = blockIdx.x;
    const int tid = threadIdx.x;       // 0..511, one dim each
    const int lane = tid & 63;
    const int wave = tid >> 6;         // 0..7

    const int p = pos[b];
    const int lo = (p - WINDOW < 0) ? 0 : (p - WINDOW);
    const int hi = (p + WINDOW > LSEQ - 1) ? (LSEQ - 1) : (p + WINDOW);
    const float inv_cnt = 1.0f / (float)(hi - lo + 1);

    // --- 3x (reduce partials, LayerNorm) -> cat_lds ---
    for (int s = 0; s < 3; ++s) {
        const float* __restrict__ part = partial + (size_t)(b * 3 + s) * NCHUNK * D;
        float v = part[tid] + part[D + tid] + part[2 * D + tid]
                + part[3 * D + tid] + part[4 * D + tid];
        v *= inv_cnt;

        float s1 = v, s2 = v * v;
        #pragma unroll
        for (int o = 32; o > 0; o >>= 1) {
            s1 += __shfl_down(s1, o, 64);
            s2 += __shfl_down(s2, o, 64);
        }
        if (lane == 0) { red[wave] = s1; red[8 + wave] = s2; }
        __syncthreads();
        float t1_ = 0.0f, t2_ = 0.0f;
        #pragma unroll
        for (int w = 0; w < 8; ++w) { t1_ += red[w]; t2_ += red[8 + w]; }
        const float mu = t1_ * (1.0f / (float)D);
        const float var = t2_ * (1.0f / (float)D) - mu * mu;
        const float rstd = rsqrtf(var + LN_EPS);

        const float* __restrict__ g  = (s == 0) ? g0  : ((s == 1) ? g1  : g2);
        const float* __restrict__ be = (s == 0) ? be0 : ((s == 1) ? be1 : be2);
        cat_lds[s * D + tid] = (v - mu) * rstd * g[tid] + be[tid];
        __syncthreads();   // protect red[] before next stream overwrites
    }

    // --- fused = gelu(cat @ Wf + bf) ---
    {
        const float4* __restrict__ x4 = (const float4*)cat_lds;
        float a0 = 0.0f, a1 = 0.0f, a2 = 0.0f, a3 = 0.0f;
        #pragma unroll 4
        for (int k4 = 0; k4 < (3 * D) / 4; ++k4) {
            const float4 x = x4[k4];
            const float* __restrict__ w = Wf + (size_t)(4 * k4) * D + tid;
            a0 += x.x * w[0];
            a1 += x.y * w[D];
            a2 += x.z * w[2 * D];
            a3 += x.w * w[3 * D];
        }
        const float acc = bf[tid] + ((a0 + a1) + (a2 + a3));
        const float ge = gelu_exact(acc);
        fused_lds[tid] = ge;
        out[3312 + b * D + tid] = ge;     // fused output block
    }
    __syncthreads();

    // --- t1 = gelu(fused @ Wt1 + bt1), 512 outputs ---
    {
        const float4* __restrict__ x4 = (const float4*)fused_lds;
        float a0 = 0.0f, a1 = 0.0f, a2 = 0.0f, a3 = 0.0f;
        #pragma unroll 4
        for (int k4 = 0; k4 < D / 4; ++k4) {
            const float4 x = x4[k4];
            const float* __restrict__ w = Wt1 + (size_t)(4 * k4) * D + tid;
            a0 += x.x * w[0];
            a1 += x.y * w[D];
            a2 += x.z * w[2 * D];
            a3 += x.w * w[3 * D];
        }
        t1_lds[tid] = gelu_exact(bt1[tid] + ((a0 + a1) + (a2 + a3)));
    }
    // --- i1 (threads 0..255) / m1 (threads 256..511), 256 outputs each ---
    if (tid < 256) {
        const float4* __restrict__ x4 = (const float4*)fused_lds;
        float a0 = 0.0f, a1 = 0.0f, a2 = 0.0f, a3 = 0.0f;
        #pragma unroll 4
        for (int k4 = 0; k4 < D / 4; ++k4) {
            const float4 x = x4[k4];
            const float* __restrict__ w = Wi1 + (size_t)(4 * k4) * 256 + tid;
            a0 += x.x * w[0];
            a1 += x.y * w[256];
            a2 += x.z * w[512];
            a3 += x.w * w[768];
        }
        i1_lds[tid] = gelu_exact(bi1[tid] + ((a0 + a1) + (a2 + a3)));
    } else {
        const int j = tid - 256;
        const float4* __restrict__ x4 = (const float4*)fused_lds;
        float a0 = 0.0f, a1 = 0.0f, a2 = 0.0f, a3 = 0.0f;
        #pragma unroll 4
        for (int k4 = 0; k4 < D / 4; ++k4) {
            const float4 x = x4[k4];
            const float* __restrict__ w = Wm1 + (size_t)(4 * k4) * 256 + j;
            a0 += x.x * w[0];
            a1 += x.y * w[256];
            a2 += x.z * w[512];
            a3 += x.w * w[768];
        }
        m1_lds[j] = gelu_exact(bm1[j] + ((a0 + a1) + (a2 + a3)));
    }
    __syncthreads();

    // --- tissue (threads 0..199) ---
    if (tid < N_TISSUES) {
        const float4* __restrict__ x4 = (const float4*)t1_lds;
        float a0 = 0.0f, a1 = 0.0f, a2 = 0.0f, a3 = 0.0f;
        #pragma unroll 4
        for (int k4 = 0; k4 < D / 4; ++k4) {
            const float4 x = x4[k4];
            const float* __restrict__ w = Wt2 + (size_t)(4 * k4) * N_TISSUES + tid;
            a0 += x.x * w[0];
            a1 += x.y * w[N_TISSUES];
            a2 += x.z * w[2 * N_TISSUES];
            a3 += x.w * w[3 * N_TISSUES];
        }
        out[16 + b * N_TISSUES + tid] = bt2[tid] + ((a0 + a1) + (a2 + a3));
    } else if (tid >= 208 && tid < 208 + N_MECH) {
        // --- mech (6 outputs) ---
        const int m = tid - 208;
        const float4* __restrict__ x4 = (const float4*)m1_lds;
        float a0 = 0.0f, a1 = 0.0f, a2 = 0.0f, a3 = 0.0f;
        #pragma unroll 4
        for (int k4 = 0; k4 < 256 / 4; ++k4) {
            const float4 x = x4[k4];
            const float* __restrict__ w = Wm2 + (size_t)(4 * k4) * N_MECH + m;
            a0 += x.x * w[0];
            a1 += x.y * w[N_MECH];
            a2 += x.z * w[2 * N_MECH];
            a3 += x.w * w[3 * N_MECH];
        }
        out[3216 + b * N_MECH + m] = bm2[m] + ((a0 + a1) + (a2 + a3));
    }
    // --- impact: threads 256..511 reduce dot(i1, Wi2) ---
    if (tid >= 256) {
        const int t = tid - 256;
        float ip = i1_lds[t] * Wi2[t];
        #pragma unroll
        for (int o = 32; o > 0; o >>= 1) ip += __shfl_down(ip, o, 64);
        if (lane == 0) red[wave] = ip;   // waves 4..7
    }
    __syncthreads();
    if (tid == 0) {
        const float x = red[4] + red[5] + red[6] + red[7] + bi2[0];
        out[b] = 1.0f / (1.0f + expf(-x));
    }
}

// ---------------------------------------------------------------------------
extern "C" void kernel_launch(void* const* d_in, const int* in_sizes, int n_in,
                              void* d_out, int out_size, void* d_ws, size_t ws_size,
                              hipStream_t stream) {
    const float* ref_local    = (const float*)d_in[0];
    const float* ref_regional = (const float*)d_in[1];
    const float* ref_macro    = (const float*)d_in[2];
    const float* alt_local    = (const float*)d_in[3];
    const float* alt_regional = (const float*)d_in[4];
    const float* alt_macro    = (const float*)d_in[5];
    const int*   pos          = (const int*)d_in[6];
    const float* g0  = (const float*)d_in[7];
    const float* be0 = (const float*)d_in[8];
    const float* g1  = (const float*)d_in[9];
    const float* be1 = (const float*)d_in[10];
    const float* g2  = (const float*)d_in[11];
    const float* be2 = (const float*)d_in[12];
    const float* Wf  = (const float*)d_in[13];
    const float* bf  = (const float*)d_in[14];
    const float* Wi1 = (const float*)d_in[15];
    const float* bi1 = (const float*)d_in[16];
    const float* Wi2 = (const float*)d_in[17];
    const float* bi2 = (const float*)d_in[18];
    const float* Wt1 = (const float*)d_in[19];
    const float* bt1 = (const float*)d_in[20];
    const float* Wt2 = (const float*)d_in[21];
    const float* bt2 = (const float*)d_in[22];
    const float* Wm1 = (const float*)d_in[23];
    const float* bm1 = (const float*)d_in[24];
    const float* Wm2 = (const float*)d_in[25];
    const float* bm2 = (const float*)d_in[26];

    float* partial = (float*)d_ws;     // NB*3*NCHUNK*D floats = 480 KiB
    float* out = (float*)d_out;

    pool_partial_kernel<<<NB * 3 * NCHUNK, 256, 0, stream>>>(
        ref_local, ref_regional, ref_macro,
        alt_local, alt_regional, alt_macro, pos, partial);

    head_kernel<<<NB, 512, 0, stream>>>(
        partial, pos, g0, be0, g1, be1, g2, be2,
        Wf, bf, Wi1, bi1, Wi2, bi2, Wt1, bt1, Wt2, bt2, Wm1, bm1, Wm2, bm2,
        out);
}

// Round 3
// 553.487 us; speedup vs baseline: 1.1247x; 1.1247x over previous
//
#include <hip/hip_runtime.h>
#include <math.h>

#define D 512
#define LSEQ 4096
#define NB 16
#define WINDOW 32
#define NCHUNK 5
#define CHUNK 13            // 5*13 = 65 = 2*WINDOW+1
#define N_TISSUES 200
#define N_MECH 6
#define LN_EPS 1e-5f

// ---- ws layout (float offsets), all contiguous ----
#define WS_PARTIAL 0                 // 16*3*5*512 = 122880
#define WS_CAT     122880            // 16*1536    = 24576
#define WS_FUSED   147456            // 16*512     =  8192  (atomic raw sums)
#define WS_H1      155648            // 16*1024    = 16384  (t1|i1|m1 raw)
#define WS_T2      172032            // 16*200     =  3200  (raw)
#define ZERO_SPAN  27776             // fused+h1+t2, zeroed by prep

__device__ __forceinline__ float gelu_exact(float x) {
    return 0.5f * x * (1.0f + erff(x * 0.70710678118654752f));
}
__device__ __forceinline__ void atom_add(float* p, float v) {
    unsafeAtomicAdd(p, v);          // native global_atomic_add_f32 on gfx950
}

// ---------------------------------------------------------------------------
// K1: windowed diff partial sums. grid = 16*3*5 = 240 blocks x 256.
// ---------------------------------------------------------------------------
__global__ __launch_bounds__(256) void pool_partial_kernel(
    const float* __restrict__ ref0, const float* __restrict__ ref1, const float* __restrict__ ref2,
    const float* __restrict__ alt0, const float* __restrict__ alt1, const float* __restrict__ alt2,
    const int* __restrict__ pos, float* __restrict__ partial)
{
    const int blk = blockIdx.x;
    const int b = blk / (3 * NCHUNK);
    const int s = (blk / NCHUNK) % 3;
    const int c = blk % NCHUNK;
    const float* __restrict__ ref = (s == 0) ? ref0 : ((s == 1) ? ref1 : ref2);
    const float* __restrict__ alt = (s == 0) ? alt0 : ((s == 1) ? alt1 : alt2);
    const int p = pos[b];
    const int tid = threadIdx.x;

    float acc0 = 0.0f, acc1 = 0.0f;
    const int base_off = -WINDOW + c * CHUNK;
    #pragma unroll
    for (int i = 0; i < CHUNK; ++i) {
        const int idx = p + base_off + i;
        if (idx >= 0 && idx < LSEQ) {
            const size_t row = ((size_t)b * LSEQ + (size_t)idx) * D;
            acc0 += alt[row + tid]       - ref[row + tid];
            acc1 += alt[row + tid + 256] - ref[row + tid + 256];
        }
    }
    float* __restrict__ outp = partial + ((size_t)(b * 3 + s) * NCHUNK + c) * D;
    outp[tid]       = acc0;
    outp[tid + 256] = acc1;
}

// ---------------------------------------------------------------------------
// K2: reduce partials + LayerNorm -> cat[16][1536]; zero atomic buffers.
// grid = 48 blocks (b,s) x 512 threads.
// ---------------------------------------------------------------------------
__global__ __launch_bounds__(512) void prep_kernel(
    const float* __restrict__ partial, const int* __restrict__ pos,
    const float* __restrict__ g0, const float* __restrict__ be0,
    const float* __restrict__ g1, const float* __restrict__ be1,
    const float* __restrict__ g2, const float* __restrict__ be2,
    float* __restrict__ cat, float* __restrict__ zero_base)
{
    __shared__ float red[16];
    const int blk = blockIdx.x;
    const int b = blk / 3;
    const int s = blk % 3;
    const int tid = threadIdx.x;
    const int lane = tid & 63;
    const int wave = tid >> 6;

    // zero the atomic accumulator span (grid-stride over 27776 floats)
    for (int i = blk * 512 + tid; i < ZERO_SPAN; i += 48 * 512)
        zero_base[i] = 0.0f;

    const int p = pos[b];
    const int lo = (p - WINDOW < 0) ? 0 : (p - WINDOW);
    const int hi = (p + WINDOW > LSEQ - 1) ? (LSEQ - 1) : (p + WINDOW);
    const float inv_cnt = 1.0f / (float)(hi - lo + 1);

    const float* __restrict__ part = partial + (size_t)(b * 3 + s) * NCHUNK * D;
    float v = part[tid] + part[D + tid] + part[2 * D + tid]
            + part[3 * D + tid] + part[4 * D + tid];
    v *= inv_cnt;

    float s1 = v, s2 = v * v;
    #pragma unroll
    for (int o = 32; o > 0; o >>= 1) {
        s1 += __shfl_down(s1, o, 64);
        s2 += __shfl_down(s2, o, 64);
    }
    if (lane == 0) { red[wave] = s1; red[8 + wave] = s2; }
    __syncthreads();
    float t1_ = 0.0f, t2_ = 0.0f;
    #pragma unroll
    for (int w = 0; w < 8; ++w) { t1_ += red[w]; t2_ += red[8 + w]; }
    const float mu = t1_ * (1.0f / (float)D);
    const float var = t2_ * (1.0f / (float)D) - mu * mu;
    const float rstd = rsqrtf(var + LN_EPS);

    const float* __restrict__ g  = (s == 0) ? g0  : ((s == 1) ? g1  : g2);
    const float* __restrict__ be = (s == 0) ? be0 : ((s == 1) ? be1 : be2);
    cat[(size_t)b * 1536 + s * D + tid] = (v - mu) * rstd * g[tid] + be[tid];
}

// ---------------------------------------------------------------------------
// K3: fused_raw[16][512] += cat @ Wf  (split-k, weights read ONCE).
// grid = 24 kc * 2 colgroups = 48 blocks x 256.
// ---------------------------------------------------------------------------
__global__ __launch_bounds__(256) void fused_mm_kernel(
    const float* __restrict__ cat, const float* __restrict__ Wf,
    float* __restrict__ fused_raw)
{
    __shared__ float xl[16 * 64];
    const int kc = blockIdx.x >> 1;          // 0..23, k chunk of 64
    const int cg = blockIdx.x & 1;           // col half
    const int tid = threadIdx.x;

    // stage cat chunk [16][64]
    {
        const int e = tid * 4;
        const int b = e >> 6, kk = e & 63;
        *(float4*)&xl[e] = *(const float4*)&cat[(size_t)b * 1536 + kc * 64 + kk];
    }
    __syncthreads();

    const int col = cg * 256 + tid;
    float acc[16];
    #pragma unroll
    for (int b = 0; b < 16; ++b) acc[b] = 0.0f;

    const float* __restrict__ wp = Wf + (size_t)(kc * 64) * D + col;
    #pragma unroll 4
    for (int kk = 0; kk < 64; ++kk) {
        const float w = wp[(size_t)kk * D];
        #pragma unroll
        for (int b = 0; b < 16; ++b) acc[b] += xl[b * 64 + kk] * w;
    }
    #pragma unroll
    for (int b = 0; b < 16; ++b) atom_add(&fused_raw[b * D + col], acc[b]);
}

// ---------------------------------------------------------------------------
// K4: h1_raw[16][1024] += gelu(bf+fused_raw) @ [Wt1|Wi1|Wm1]; writes fused out.
// grid = 8 kc * 4 colgroups = 32 blocks x 256.
// ---------------------------------------------------------------------------
__global__ __launch_bounds__(256) void h1_mm_kernel(
    const float* __restrict__ fused_raw, const float* __restrict__ bf,
    const float* __restrict__ Wt1, const float* __restrict__ Wi1,
    const float* __restrict__ Wm1,
    float* __restrict__ h1_raw, float* __restrict__ out)
{
    __shared__ float xl[16 * 64];
    const int kc = blockIdx.x >> 2;          // 0..7, k chunk of 64
    const int cg = blockIdx.x & 3;           // 0,1: t1 cols; 2: i1; 3: m1
    const int tid = threadIdx.x;

    // stage fused chunk [16][64] = gelu(bf + fused_raw)
    {
        const int e = tid * 4;
        const int b = e >> 6, kk = e & 63;
        const float4 r = *(const float4*)&fused_raw[(size_t)b * D + kc * 64 + kk];
        const float4 bb = *(const float4*)&bf[kc * 64 + kk];
        float4 gg;
        gg.x = gelu_exact(r.x + bb.x); gg.y = gelu_exact(r.y + bb.y);
        gg.z = gelu_exact(r.z + bb.z); gg.w = gelu_exact(r.w + bb.w);
        *(float4*)&xl[e] = gg;
        if (cg == 0) *(float4*)&out[3312 + (size_t)b * D + kc * 64 + kk] = gg;
    }
    __syncthreads();

    const int col = cg * 256 + tid;          // 0..1023 in [t1|i1|m1] space
    const float* __restrict__ wp;
    int ldw;
    if (cg < 2)      { wp = Wt1 + (size_t)(kc * 64) * D + col;          ldw = D;   }
    else if (cg == 2){ wp = Wi1 + (size_t)(kc * 64) * 256 + (col - 512); ldw = 256; }
    else             { wp = Wm1 + (size_t)(kc * 64) * 256 + (col - 768); ldw = 256; }

    float acc[16];
    #pragma unroll
    for (int b = 0; b < 16; ++b) acc[b] = 0.0f;
    #pragma unroll 4
    for (int kk = 0; kk < 64; ++kk) {
        const float w = wp[(size_t)kk * ldw];
        #pragma unroll
        for (int b = 0; b < 16; ++b) acc[b] += xl[b * 64 + kk] * w;
    }
    #pragma unroll
    for (int b = 0; b < 16; ++b) atom_add(&h1_raw[b * 1024 + col], acc[b]);
}

// ---------------------------------------------------------------------------
// K5: blocks 0..7: t2_raw += gelu(bt1+t1_raw) @ Wt2 (split-k).
//     block 8: mech + impact heads in full (LDS-staged i1/m1).
// ---------------------------------------------------------------------------
__global__ __launch_bounds__(256) void small_heads_kernel(
    const float* __restrict__ h1_raw,
    const float* __restrict__ bt1, const float* __restrict__ bi1,
    const float* __restrict__ bm1,
    const float* __restrict__ Wt2, const float* __restrict__ Wm2,
    const float* __restrict__ Wi2, const float* __restrict__ bm2,
    const float* __restrict__ bi2,
    float* __restrict__ t2_raw, float* __restrict__ out)
{
    __shared__ float s[8192];                 // 32 KiB
    const int tid = threadIdx.x;

    if (blockIdx.x < 8) {
        const int kc = blockIdx.x;            // k chunk of 64 over t1
        // stage t1 chunk [16][64] = gelu(bt1 + h1_raw[:, 0:512])
        {
            const int e = tid * 4;
            const int b = e >> 6, kk = e & 63;
            const float4 r = *(const float4*)&h1_raw[(size_t)b * 1024 + kc * 64 + kk];
            const float4 bb = *(const float4*)&bt1[kc * 64 + kk];
            s[e]     = gelu_exact(r.x + bb.x);
            s[e + 1] = gelu_exact(r.y + bb.y);
            s[e + 2] = gelu_exact(r.z + bb.z);
            s[e + 3] = gelu_exact(r.w + bb.w);
        }
        __syncthreads();
        if (tid < N_TISSUES) {
            const float* __restrict__ wp = Wt2 + (size_t)(kc * 64) * N_TISSUES + tid;
            float acc[16];
            #pragma unroll
            for (int b = 0; b < 16; ++b) acc[b] = 0.0f;
            #pragma unroll 4
            for (int kk = 0; kk < 64; ++kk) {
                const float w = wp[(size_t)kk * N_TISSUES];
                #pragma unroll
                for (int b = 0; b < 16; ++b) acc[b] += s[b * 64 + kk] * w;
            }
            #pragma unroll
            for (int b = 0; b < 16; ++b) atom_add(&t2_raw[b * N_TISSUES + tid], acc[b]);
        }
    } else {
        // stage i1[16][256] and m1[16][256] with bias+gelu
        for (int b = 0; b < 16; ++b) {
            s[b * 256 + tid]        = gelu_exact(bi1[tid] + h1_raw[(size_t)b * 1024 + 512 + tid]);
            s[4096 + b * 256 + tid] = gelu_exact(bm1[tid] + h1_raw[(size_t)b * 1024 + 768 + tid]);
        }
        __syncthreads();
        if (tid < 96) {                       // mech: t = b*6+m
            const int b = tid / 6, m = tid % 6;
            float a0 = 0, a1 = 0, a2 = 0, a3 = 0;
            for (int j = 0; j < 256; j += 4) {
                a0 += s[4096 + b * 256 + j]     * Wm2[(j)     * N_MECH + m];
                a1 += s[4096 + b * 256 + j + 1] * Wm2[(j + 1) * N_MECH + m];
                a2 += s[4096 + b * 256 + j + 2] * Wm2[(j + 2) * N_MECH + m];
                a3 += s[4096 + b * 256 + j + 3] * Wm2[(j + 3) * N_MECH + m];
            }
            out[3216 + tid] = bm2[m] + ((a0 + a1) + (a2 + a3));
        } else if (tid < 112) {               // impact: b = tid-96
            const int b = tid - 96;
            float a0 = 0, a1 = 0, a2 = 0, a3 = 0;
            for (int j = 0; j < 256; j += 4) {
                a0 += s[b * 256 + j]     * Wi2[j];
                a1 += s[b * 256 + j + 1] * Wi2[j + 1];
                a2 += s[b * 256 + j + 2] * Wi2[j + 2];
                a3 += s[b * 256 + j + 3] * Wi2[j + 3];
            }
            const float x = bi2[0] + ((a0 + a1) + (a2 + a3));
            out[b] = 1.0f / (1.0f + expf(-x));
        }
    }
}

// ---------------------------------------------------------------------------
// K6: tissue bias-add finalize. 13 blocks x 256.
// ---------------------------------------------------------------------------
__global__ __launch_bounds__(256) void t2_final_kernel(
    const float* __restrict__ t2_raw, const float* __restrict__ bt2,
    float* __restrict__ out)
{
    const int gid = blockIdx.x * 256 + threadIdx.x;
    if (gid < NB * N_TISSUES) {
        const int c = gid % N_TISSUES;
        out[16 + gid] = bt2[c] + t2_raw[gid];
    }
}

// ---------------------------------------------------------------------------
extern "C" void kernel_launch(void* const* d_in, const int* in_sizes, int n_in,
                              void* d_out, int out_size, void* d_ws, size_t ws_size,
                              hipStream_t stream) {
    const float* ref_local    = (const float*)d_in[0];
    const float* ref_regional = (const float*)d_in[1];
    const float* ref_macro    = (const float*)d_in[2];
    const float* alt_local    = (const float*)d_in[3];
    const float* alt_regional = (const float*)d_in[4];
    const float* alt_macro    = (const float*)d_in[5];
    const int*   pos          = (const int*)d_in[6];
    const float* g0  = (const float*)d_in[7];
    const float* be0 = (const float*)d_in[8];
    const float* g1  = (const float*)d_in[9];
    const float* be1 = (const float*)d_in[10];
    const float* g2  = (const float*)d_in[11];
    const float* be2 = (const float*)d_in[12];
    const float* Wf  = (const float*)d_in[13];
    const float* bf  = (const float*)d_in[14];
    const float* Wi1 = (const float*)d_in[15];
    const float* bi1 = (const float*)d_in[16];
    const float* Wi2 = (const float*)d_in[17];
    const float* bi2 = (const float*)d_in[18];
    const float* Wt1 = (const float*)d_in[19];
    const float* bt1 = (const float*)d_in[20];
    const float* Wt2 = (const float*)d_in[21];
    const float* bt2 = (const float*)d_in[22];
    const float* Wm1 = (const float*)d_in[23];
    const float* bm1 = (const float*)d_in[24];
    const float* Wm2 = (const float*)d_in[25];
    const float* bm2 = (const float*)d_in[26];

    float* ws        = (float*)d_ws;
    float* partial   = ws + WS_PARTIAL;
    float* cat       = ws + WS_CAT;
    float* fused_raw = ws + WS_FUSED;
    float* h1_raw    = ws + WS_H1;
    float* t2_raw    = ws + WS_T2;
    float* out       = (float*)d_out;

    pool_partial_kernel<<<NB * 3 * NCHUNK, 256, 0, stream>>>(
        ref_local, ref_regional, ref_macro,
        alt_local, alt_regional, alt_macro, pos, partial);

    prep_kernel<<<48, 512, 0, stream>>>(
        partial, pos, g0, be0, g1, be1, g2, be2, cat, fused_raw /*zero base*/);

    fused_mm_kernel<<<48, 256, 0, stream>>>(cat, Wf, fused_raw);

    h1_mm_kernel<<<32, 256, 0, stream>>>(fused_raw, bf, Wt1, Wi1, Wm1, h1_raw, out);

    small_heads_kernel<<<9, 256, 0, stream>>>(
        h1_raw, bt1, bi1, bm1, Wt2, Wm2, Wi2, bm2, bi2, t2_raw, out);

    t2_final_kernel<<<13, 256, 0, stream>>>(t2_raw, bt2, out);
}

// Round 4
// 552.406 us; speedup vs baseline: 1.1269x; 1.0020x over previous
//
#include <hip/hip_runtime.h>
#include <math.h>

#define D 512
#define LSEQ 4096
#define NB 16
#define WINDOW 32
#define NCHUNK 10
#define CHUNK 7             // 10*7 = 70 >= 65 = 2*WINDOW+1 (j<65 guard)
#define N_TISSUES 200
#define N_MECH 6
#define LN_EPS 1e-5f

// ---- ws layout (float offsets) ----
#define WS_PARTIAL 0                 // 16*3*10*512 = 245760
#define WS_CAT     245760            // 16*1536     = 24576
#define WS_FUSED   270336            // 16*512      = 8192   (atomic raw)
#define WS_H1      278528            // 16*1024     = 16384  (atomic raw)
#define ZERO_SPAN  24576             // fused+h1, zeroed by pool_zero blocks

__device__ __forceinline__ float gelu_exact(float x) {
    return 0.5f * x * (1.0f + erff(x * 0.70710678118654752f));
}
__device__ __forceinline__ void atom_add(float* p, float v) {
    unsafeAtomicAdd(p, v);          // native global_atomic_add_f32
}

// ---------------------------------------------------------------------------
// K1: blocks 0..479: windowed diff partial sums (7 rows each, float2 loads).
//     blocks 480..487: zero the atomic accumulators (fused_raw + h1_raw).
// ---------------------------------------------------------------------------
__global__ __launch_bounds__(256) void pool_zero_kernel(
    const float* __restrict__ ref0, const float* __restrict__ ref1, const float* __restrict__ ref2,
    const float* __restrict__ alt0, const float* __restrict__ alt1, const float* __restrict__ alt2,
    const int* __restrict__ pos, float* __restrict__ partial,
    float* __restrict__ zero_base)
{
    const int blk = blockIdx.x;
    const int tid = threadIdx.x;

    if (blk >= 480) {
        for (int i = (blk - 480) * 256 + tid; i < ZERO_SPAN; i += 8 * 256)
            zero_base[i] = 0.0f;
        return;
    }

    const int b = blk / 30;
    const int r = blk % 30;
    const int s = r / NCHUNK;
    const int c = r % NCHUNK;
    const float* __restrict__ ref = (s == 0) ? ref0 : ((s == 1) ? ref1 : ref2);
    const float* __restrict__ alt = (s == 0) ? alt0 : ((s == 1) ? alt1 : alt2);
    const int p = pos[b];

    float acc0 = 0.0f, acc1 = 0.0f;
    #pragma unroll
    for (int i = 0; i < CHUNK; ++i) {
        const int j = c * CHUNK + i;             // 0..69 window slot
        const int idx = p + j - WINDOW;
        if (j < 65 && idx >= 0 && idx < LSEQ) {
            const size_t row = ((size_t)b * LSEQ + (size_t)idx) * D;
            const float2 a2 = *(const float2*)&alt[row + 2 * tid];
            const float2 r2 = *(const float2*)&ref[row + 2 * tid];
            acc0 += a2.x - r2.x;
            acc1 += a2.y - r2.y;
        }
    }
    float2 o; o.x = acc0; o.y = acc1;
    *(float2*)&partial[((size_t)(b * 3 + s) * NCHUNK + c) * D + 2 * tid] = o;
}

// ---------------------------------------------------------------------------
// K2: reduce 10 partials + LayerNorm -> cat[16][1536]. 48 blocks x 512.
// ---------------------------------------------------------------------------
__global__ __launch_bounds__(512) void prep_kernel(
    const float* __restrict__ partial, const int* __restrict__ pos,
    const float* __restrict__ g0, const float* __restrict__ be0,
    const float* __restrict__ g1, const float* __restrict__ be1,
    const float* __restrict__ g2, const float* __restrict__ be2,
    float* __restrict__ cat)
{
    __shared__ float red[16];
    const int blk = blockIdx.x;
    const int b = blk / 3;
    const int s = blk % 3;
    const int tid = threadIdx.x;
    const int lane = tid & 63;
    const int wave = tid >> 6;

    const int p = pos[b];
    const int lo = (p - WINDOW < 0) ? 0 : (p - WINDOW);
    const int hi = (p + WINDOW > LSEQ - 1) ? (LSEQ - 1) : (p + WINDOW);
    const float inv_cnt = 1.0f / (float)(hi - lo + 1);

    const float* __restrict__ part = partial + (size_t)(b * 3 + s) * NCHUNK * D;
    float v = 0.0f;
    #pragma unroll
    for (int c = 0; c < NCHUNK; ++c) v += part[c * D + tid];
    v *= inv_cnt;

    float s1 = v, s2 = v * v;
    #pragma unroll
    for (int o = 32; o > 0; o >>= 1) {
        s1 += __shfl_down(s1, o, 64);
        s2 += __shfl_down(s2, o, 64);
    }
    if (lane == 0) { red[wave] = s1; red[8 + wave] = s2; }
    __syncthreads();
    float t1_ = 0.0f, t2_ = 0.0f;
    #pragma unroll
    for (int w = 0; w < 8; ++w) { t1_ += red[w]; t2_ += red[8 + w]; }
    const float mu = t1_ * (1.0f / (float)D);
    const float var = t2_ * (1.0f / (float)D) - mu * mu;
    const float rstd = rsqrtf(var + LN_EPS);

    const float* __restrict__ g  = (s == 0) ? g0  : ((s == 1) ? g1  : g2);
    const float* __restrict__ be = (s == 0) ? be0 : ((s == 1) ? be1 : be2);
    cat[(size_t)b * 1536 + s * D + tid] = (v - mu) * rstd * g[tid] + be[tid];
}

// ---------------------------------------------------------------------------
// K3: fused_raw[16][512] += cat @ Wf (split-k, Wf read once). 48 blocks x 256.
// ---------------------------------------------------------------------------
__global__ __launch_bounds__(256) void fused_mm_kernel(
    const float* __restrict__ cat, const float* __restrict__ Wf,
    float* __restrict__ fused_raw)
{
    __shared__ float xl[16 * 64];
    const int kc = blockIdx.x >> 1;          // 0..23, k chunk of 64
    const int cg = blockIdx.x & 1;           // col half
    const int tid = threadIdx.x;

    {
        const int e = tid * 4;
        const int b = e >> 6, kk = e & 63;
        *(float4*)&xl[e] = *(const float4*)&cat[(size_t)b * 1536 + kc * 64 + kk];
    }
    __syncthreads();

    const int col = cg * 256 + tid;
    float acc[16];
    #pragma unroll
    for (int b = 0; b < 16; ++b) acc[b] = 0.0f;

    const float* __restrict__ wp = Wf + (size_t)(kc * 64) * D + col;
    #pragma unroll 4
    for (int kk = 0; kk < 64; ++kk) {
        const float w = wp[(size_t)kk * D];
        #pragma unroll
        for (int b = 0; b < 16; ++b) acc[b] += xl[b * 64 + kk] * w;
    }
    #pragma unroll
    for (int b = 0; b < 16; ++b) atom_add(&fused_raw[b * D + col], acc[b]);
}

// ---------------------------------------------------------------------------
// K4: h1_raw[16][1024] += gelu(bf+fused_raw) @ [Wt1|Wi1|Wm1]; writes fused out.
// grid = 8 kc * 4 colgroups = 32 blocks x 256.
// ---------------------------------------------------------------------------
__global__ __launch_bounds__(256) void h1_mm_kernel(
    const float* __restrict__ fused_raw, const float* __restrict__ bf,
    const float* __restrict__ Wt1, const float* __restrict__ Wi1,
    const float* __restrict__ Wm1,
    float* __restrict__ h1_raw, float* __restrict__ out)
{
    __shared__ float xl[16 * 64];
    const int kc = blockIdx.x >> 2;          // 0..7, k chunk of 64
    const int cg = blockIdx.x & 3;           // 0,1: t1 cols; 2: i1; 3: m1
    const int tid = threadIdx.x;

    {
        const int e = tid * 4;
        const int b = e >> 6, kk = e & 63;
        const float4 r = *(const float4*)&fused_raw[(size_t)b * D + kc * 64 + kk];
        const float4 bb = *(const float4*)&bf[kc * 64 + kk];
        float4 gg;
        gg.x = gelu_exact(r.x + bb.x); gg.y = gelu_exact(r.y + bb.y);
        gg.z = gelu_exact(r.z + bb.z); gg.w = gelu_exact(r.w + bb.w);
        *(float4*)&xl[e] = gg;
        if (cg == 0) *(float4*)&out[3312 + (size_t)b * D + kc * 64 + kk] = gg;
    }
    __syncthreads();

    const int col = cg * 256 + tid;
    const float* __restrict__ wp;
    int ldw;
    if (cg < 2)      { wp = Wt1 + (size_t)(kc * 64) * D + col;           ldw = D;   }
    else if (cg == 2){ wp = Wi1 + (size_t)(kc * 64) * 256 + (col - 512); ldw = 256; }
    else             { wp = Wm1 + (size_t)(kc * 64) * 256 + (col - 768); ldw = 256; }

    float acc[16];
    #pragma unroll
    for (int b = 0; b < 16; ++b) acc[b] = 0.0f;
    #pragma unroll 4
    for (int kk = 0; kk < 64; ++kk) {
        const float w = wp[(size_t)kk * ldw];
        #pragma unroll
        for (int b = 0; b < 16; ++b) acc[b] += xl[b * 64 + kk] * w;
    }
    #pragma unroll
    for (int b = 0; b < 16; ++b) atom_add(&h1_raw[b * 1024 + col], acc[b]);
}

// ---------------------------------------------------------------------------
// K5: blocks 0..7: tissue, 25 cols each, full K=512, direct write (no atomics).
//     block 8: mech + impact. 9 blocks x 512.
// ---------------------------------------------------------------------------
__global__ __launch_bounds__(512) void heads_kernel(
    const float* __restrict__ h1_raw,
    const float* __restrict__ bt1, const float* __restrict__ bi1,
    const float* __restrict__ bm1,
    const float* __restrict__ Wt2, const float* __restrict__ bt2,
    const float* __restrict__ Wm2, const float* __restrict__ bm2,
    const float* __restrict__ Wi2, const float* __restrict__ bi2,
    float* __restrict__ out)
{
    __shared__ float s[16 * 516];             // 33 KB (padded stride vs banks)
    const int tid = threadIdx.x;

    if (blockIdx.x < 8) {
        // stage t1[b][c] = gelu(bt1[c] + h1_raw[b][c]), padded stride 516
        const float btc = bt1[tid];
        #pragma unroll
        for (int b = 0; b < 16; ++b)
            s[b * 516 + tid] = gelu_exact(btc + h1_raw[(size_t)b * 1024 + tid]);
        __syncthreads();

        if (tid < 400) {
            const int col_l = tid % 25;
            const int b     = tid / 25;
            const int col   = blockIdx.x * 25 + col_l;
            const float* __restrict__ wp = Wt2 + col;
            const float* __restrict__ xp = s + b * 516;
            float a0 = 0, a1 = 0, a2 = 0, a3 = 0;
            #pragma unroll 4
            for (int k = 0; k < D; k += 4) {
                a0 += xp[k]     * wp[(size_t)k * N_TISSUES];
                a1 += xp[k + 1] * wp[(size_t)(k + 1) * N_TISSUES];
                a2 += xp[k + 2] * wp[(size_t)(k + 2) * N_TISSUES];
                a3 += xp[k + 3] * wp[(size_t)(k + 3) * N_TISSUES];
            }
            out[16 + b * N_TISSUES + col] = bt2[col] + ((a0 + a1) + (a2 + a3));
        }
    } else {
        // stage i1 (s[0..4095]) and m1 (s[4096..8191]) with bias+gelu
        if (tid < 256) {
            const float bic = bi1[tid];
            #pragma unroll
            for (int b = 0; b < 16; ++b)
                s[b * 256 + tid] = gelu_exact(bic + h1_raw[(size_t)b * 1024 + 512 + tid]);
        } else {
            const int j = tid - 256;
            const float bmc = bm1[j];
            #pragma unroll
            for (int b = 0; b < 16; ++b)
                s[4096 + b * 256 + j] = gelu_exact(bmc + h1_raw[(size_t)b * 1024 + 768 + j]);
        }
        __syncthreads();

        if (tid < 96) {                       // mech: tid = b*6+m
            const int b = tid / 6, m = tid % 6;
            float a0 = 0, a1 = 0, a2 = 0, a3 = 0;
            for (int j = 0; j < 256; j += 4) {
                a0 += s[4096 + b * 256 + j]     * Wm2[(j)     * N_MECH + m];
                a1 += s[4096 + b * 256 + j + 1] * Wm2[(j + 1) * N_MECH + m];
                a2 += s[4096 + b * 256 + j + 2] * Wm2[(j + 2) * N_MECH + m];
                a3 += s[4096 + b * 256 + j + 3] * Wm2[(j + 3) * N_MECH + m];
            }
            out[3216 + tid] = bm2[m] + ((a0 + a1) + (a2 + a3));
        } else if (tid < 112) {               // impact: b = tid-96
            const int b = tid - 96;
            float a0 = 0, a1 = 0, a2 = 0, a3 = 0;
            for (int j = 0; j < 256; j += 4) {
                a0 += s[b * 256 + j]     * Wi2[j];
                a1 += s[b * 256 + j + 1] * Wi2[j + 1];
                a2 += s[b * 256 + j + 2] * Wi2[j + 2];
                a3 += s[b * 256 + j + 3] * Wi2[j + 3];
            }
            const float x = bi2[0] + ((a0 + a1) + (a2 + a3));
            out[b] = 1.0f / (1.0f + expf(-x));
        }
    }
}

// ---------------------------------------------------------------------------
extern "C" void kernel_launch(void* const* d_in, const int* in_sizes, int n_in,
                              void* d_out, int out_size, void* d_ws, size_t ws_size,
                              hipStream_t stream) {
    const float* ref_local    = (const float*)d_in[0];
    const float* ref_regional = (const float*)d_in[1];
    const float* ref_macro    = (const float*)d_in[2];
    const float* alt_local    = (const float*)d_in[3];
    const float* alt_regional = (const float*)d_in[4];
    const float* alt_macro    = (const float*)d_in[5];
    const int*   pos          = (const int*)d_in[6];
    const float* g0  = (const float*)d_in[7];
    const float* be0 = (const float*)d_in[8];
    const float* g1  = (const float*)d_in[9];
    const float* be1 = (const float*)d_in[10];
    const float* g2  = (const float*)d_in[11];
    const float* be2 = (const float*)d_in[12];
    const float* Wf  = (const float*)d_in[13];
    const float* bf  = (const float*)d_in[14];
    const float* Wi1 = (const float*)d_in[15];
    const float* bi1 = (const float*)d_in[16];
    const float* Wi2 = (const float*)d_in[17];
    const float* bi2 = (const float*)d_in[18];
    const float* Wt1 = (const float*)d_in[19];
    const float* bt1 = (const float*)d_in[20];
    const float* Wt2 = (const float*)d_in[21];
    const float* bt2 = (const float*)d_in[22];
    const float* Wm1 = (const float*)d_in[23];
    const float* bm1 = (const float*)d_in[24];
    const float* Wm2 = (const float*)d_in[25];
    const float* bm2 = (const float*)d_in[26];

    float* ws        = (float*)d_ws;
    float* partial   = ws + WS_PARTIAL;
    float* cat       = ws + WS_CAT;
    float* fused_raw = ws + WS_FUSED;
    float* h1_raw    = ws + WS_H1;
    float* out       = (float*)d_out;

    pool_zero_kernel<<<488, 256, 0, stream>>>(
        ref_local, ref_regional, ref_macro,
        alt_local, alt_regional, alt_macro, pos, partial, fused_raw /*zero base*/);

    prep_kernel<<<48, 512, 0, stream>>>(
        partial, pos, g0, be0, g1, be1, g2, be2, cat);

    fused_mm_kernel<<<48, 256, 0, stream>>>(cat, Wf, fused_raw);

    h1_mm_kernel<<<32, 256, 0, stream>>>(fused_raw, bf, Wt1, Wi1, Wm1, h1_raw, out);

    heads_kernel<<<9, 512, 0, stream>>>(
        h1_raw, bt1, bi1, bm1, Wt2, bt2, Wm2, bm2, Wi2, bi2, out);
}